// Round 2
// baseline (574.505 us; speedup 1.0000x reference)
//
#include <hip/hip_runtime.h>

// Problem constants
#define NB     64      // batch
#define TT     2048    // time
#define INQ    8       // input size
#define CC     2       // channels
#define MM     10      // hidden m
#define ROWP   12      // padded row floats (48 B)
#define MATS   124     // matrix stride in LDS tree (124%32=28)
#define PSTR   20      // skp row stride floats (16B-aligned)
#define BLK    512     // threads per block (8 waves)
#define SEGS   128     // segments per block (512 thr / 4 lanes)
#define SLEN   4       // sequential steps per quad segment
#define NCHK   4       // chunks per chain -> grid 512, 2 blocks/CU, one round
#define NCHAIN (NB*CC)

typedef float v2f __attribute__((ext_vector_type(2)));

// Upper-triangle index for (k,j), k<j, into 45-element array
__device__ __forceinline__ constexpr int triIdx(int k, int j) {
    return k * 10 + j - ((k + 1) * (k + 2)) / 2;
}

// Broadcast lane (quad base + SRC)'s value to all 4 lanes of the quad.
template <int SRC>
__device__ __forceinline__ float dpp_qbcast(float v) {
    const int i = __float_as_int(v);
    const int r = __builtin_amdgcn_update_dpp(i, i, SRC * 0x55, 0xF, 0xF, true);
    return __int_as_float(r);
}

// One Taylor row-stream, packed pair of rows: t = S*G; A = t; R += cj*t.
// Row r of S*G depends only on row r of S -> in-place safe (S may alias A).
__device__ __forceinline__ void trow_pk(const float* __restrict__ Tri,
                                        v2f* A, v2f* R, const v2f* S, float cj) {
    v2f t[MM];
    t[0] = -S[1] * Tri[triIdx(0, 1)];
    #pragma unroll
    for (int j = 1; j < MM; ++j) t[j] = S[0] * Tri[triIdx(0, j)];
    #pragma unroll
    for (int k = 1; k < MM; ++k) {
        const v2f a = S[k];
        #pragma unroll
        for (int j = 0; j < MM; ++j) {
            if (k == j) continue;
            if (j == 0 && k == 1) continue;
            if (j > k) t[j] += a * Tri[triIdx(k, j)];
            else       t[j] -= a * Tri[triIdx(j, k)];
        }
    }
    #pragma unroll
    for (int j = 0; j < MM; ++j) { A[j] = t[j]; R[j] += cj * t[j]; }
}

__device__ __forceinline__ void trow_s(const float* __restrict__ Tri,
                                       float* A, float* R, const float* S, float cj) {
    float t[MM];
    t[0] = -S[1] * Tri[triIdx(0, 1)];
    #pragma unroll
    for (int j = 1; j < MM; ++j) t[j] = S[0] * Tri[triIdx(0, j)];
    #pragma unroll
    for (int k = 1; k < MM; ++k) {
        const float a = S[k];
        #pragma unroll
        for (int j = 0; j < MM; ++j) {
            if (k == j) continue;
            if (j == 0 && k == 1) continue;
            if (j > k) t[j] += a * Tri[triIdx(k, j)];
            else       t[j] -= a * Tri[triIdx(j, k)];
        }
    }
    #pragma unroll
    for (int j = 0; j < MM; ++j) { A[j] = t[j]; R[j] += cj * t[j]; }
}

// 2-lane pair combine: buf[ls] <- buf[ls] * buf[rs] (pq = which 5-row half)
__device__ __forceinline__ void pair_combine(float* buf_s, int ls, int rs, int pq) {
    float lrow[5][MM];
    #pragma unroll
    for (int r = 0; r < 5; ++r) {
        const float4* lr = reinterpret_cast<const float4*>(
            &buf_s[ls * MATS + (pq * 5 + r) * ROWP]);
        const float4 a = lr[0], b = lr[1], c4 = lr[2];
        lrow[r][0] = a.x;  lrow[r][1] = a.y;  lrow[r][2] = a.z;  lrow[r][3] = a.w;
        lrow[r][4] = b.x;  lrow[r][5] = b.y;  lrow[r][6] = b.z;  lrow[r][7] = b.w;
        lrow[r][8] = c4.x; lrow[r][9] = c4.y;
    }
    float d[5][MM];
    #pragma unroll
    for (int r = 0; r < 5; ++r)
        #pragma unroll
        for (int j = 0; j < MM; ++j)
            d[r][j] = 0.0f;
    #pragma unroll
    for (int k = 0; k < MM; ++k) {
        const float4* rr = reinterpret_cast<const float4*>(&buf_s[rs * MATS + k * ROWP]);
        const float4 a = rr[0], b = rr[1], c4 = rr[2];
        float rrow[MM];
        rrow[0] = a.x;  rrow[1] = a.y;  rrow[2] = a.z;  rrow[3] = a.w;
        rrow[4] = b.x;  rrow[5] = b.y;  rrow[6] = b.z;  rrow[7] = b.w;
        rrow[8] = c4.x; rrow[9] = c4.y;
        #pragma unroll
        for (int r = 0; r < 5; ++r) {
            const float lv = lrow[r][k];
            #pragma unroll
            for (int j = 0; j < MM; ++j)
                d[r][j] += lv * rrow[j];
        }
    }
    float* dst = &buf_s[ls * MATS + pq * 5 * ROWP];
    #pragma unroll
    for (int r = 0; r < 5; ++r) {
        float4* drow = reinterpret_cast<float4*>(dst + r * ROWP);
        drow[0] = make_float4(d[r][0], d[r][1], d[r][2], d[r][3]);
        drow[1] = make_float4(d[r][4], d[r][5], d[r][6], d[r][7]);
        drow[2] = make_float4(d[r][8], d[r][9], 0.0f, 0.0f);
    }
}

// r15: cross the 128-VGPR occupancy cliff (152 VGPR allocates at the 256-step
// -> only 2 waves/SIMD; r14 proved grid scaling alone can't help). Cuts:
// (a) no x double-buffer (reload x[t],x[t+1] each step, L1-hit), (b) pk/s
// Taylor phases split so A01/A2 never co-live. __launch_bounds__(512,4)
// enforces <=128 VGPR -> 4 waves/SIMD. Block reshaped to 512 thr / SEGS=128 /
// SLEN=4 with NCHK=4 so grid 512 = 2 blocks/CU = 16 waves/CU in ONE round,
// same tree count as r12 (one extra level, high-parallelism at top).
// LDS 65,408 B/block; 2 blocks = 131 KB <= 160 KB.
// Taylor rows: q0 pk{0,1}+s{2}, q1 pk{3,4}+s{5}, q2 pk{6,7}, q3 pk{8,9}
// (q2/q3 scalar stream is dummy row 9). KTAY=5: trunc ~1.5e-6/step,
// ~3e-3 accumulated — inside the 1.95e-2 budget (absmax was 0.0078).
__global__ __launch_bounds__(BLK, 4)
void dev_serial(const float* __restrict__ x,
                const float* __restrict__ A,
                float* __restrict__ ws)
{
    __shared__ __align__(16) float skp_s[24 * PSTR];    // 1920 B pair-interleaved
    __shared__ __align__(16) float buf_s[SEGS * MATS];  // 63488 B tree buffer

    const int tid   = threadIdx.x;
    const int chain = blockIdx.x >> 2;   // / NCHK
    const int qt    = blockIdx.x & 3;
    const int n     = chain >> 1;        // / CC
    const int c     = chain & 1;

    // skp[p][ip] = v2f{ sktri[2p][ip], sktri[2p+1][ip] }, rows >=45 zero.
    for (int e = tid; e < 24 * 16; e += BLK) {
        const int p   = e >> 4;
        const int rem = e & 15;
        const int ip  = rem >> 1;
        const int h   = rem & 1;
        const int t   = 2 * p + h;
        float v = 0.0f;
        if (t < 45) {
            int k = 0, r2 = t;
            while (r2 >= 9 - k) { r2 -= (9 - k); ++k; }
            const int j = k + 1 + r2;
            const float* Ab = A + (size_t)(c * INQ + ip) * (MM * MM);
            v = Ab[k * MM + j] - Ab[j * MM + k];
        }
        skp_s[p * PSTR + 2 * ip + h] = v;
    }
    for (int p = tid; p < 24; p += BLK) {
        skp_s[p * PSTR + 16] = 0.0f; skp_s[p * PSTR + 17] = 0.0f;
        skp_s[p * PSTR + 18] = 0.0f; skp_s[p * PSTR + 19] = 0.0f;
    }
    __syncthreads();

    const int seg = tid >> 2;
    const int q   = tid & 3;                        // lane within quad
    const int p0  = (q < 2) ? 3 * q : (q == 2 ? 6 : 8);  // packed pair rows
    const int sr  = (q < 2) ? (3 * q + 2) : 9;      // scalar row (dummy on q>=2)
    const bool hasS = (q < 2);

    v2f   R01[MM];
    float R2[MM];
    #pragma unroll
    for (int j = 0; j < MM; ++j) {
        R01[j] = (v2f){ (j == p0) ? 1.0f : 0.0f, (j == p0 + 1) ? 1.0f : 0.0f };
        R2[j]  = (j == sr) ? 1.0f : 0.0f;
    }

    const float4* px = reinterpret_cast<const float4*>(x + (size_t)n * TT * INQ);
    const int t0 = qt * (SEGS * SLEN) + seg * SLEN;   // max t0 = 2044

    #pragma unroll 1
    for (int s = 0; s < SLEN; ++s) {
        // Fresh loads each step (no live x-state across the Taylor body):
        // t <= 2047; t+1 clamped to 2047 makes the last increment zero (=I).
        const int t = t0 + s;
        int t1 = t + 1; if (t1 > TT - 1) t1 = TT - 1;
        const float4 a0 = px[2 * t],  a1 = px[2 * t + 1];
        const float4 b0 = px[2 * t1], b1 = px[2 * t1 + 1];
        float dx[INQ];
        dx[0] = b0.x - a0.x; dx[1] = b0.y - a0.y;
        dx[2] = b0.z - a0.z; dx[3] = b0.w - a0.w;
        dx[4] = b1.x - a1.x; dx[5] = b1.y - a1.y;
        dx[6] = b1.z - a1.z; dx[7] = b1.w - a1.w;

        // Packed tv: tvp[pp] = (tri[12q+2pp], tri[12q+2pp+1])
        v2f tvp[6];
        #pragma unroll
        for (int pp = 0; pp < 6; ++pp) {
            const v2f* sp = reinterpret_cast<const v2f*>(&skp_s[(6 * q + pp) * PSTR]);
            v2f acc = dx[0] * sp[0];
            #pragma unroll
            for (int ip = 1; ip < INQ; ++ip)
                acc += dx[ip] * sp[ip];
            tvp[pp] = acc;
        }
        float tv[12];
        #pragma unroll
        for (int pp = 0; pp < 6; ++pp) { tv[2 * pp] = tvp[pp].x; tv[2 * pp + 1] = tvp[pp].y; }

        // Assemble Tri[45] per-lane via DPP quad broadcast
        float Tri[45];
        #define TRIFILL(U) Tri[U] = dpp_qbcast<(U) / 12>(tv[(U) % 12]);
        TRIFILL(0)  TRIFILL(1)  TRIFILL(2)  TRIFILL(3)  TRIFILL(4)
        TRIFILL(5)  TRIFILL(6)  TRIFILL(7)  TRIFILL(8)  TRIFILL(9)
        TRIFILL(10) TRIFILL(11) TRIFILL(12) TRIFILL(13) TRIFILL(14)
        TRIFILL(15) TRIFILL(16) TRIFILL(17) TRIFILL(18) TRIFILL(19)
        TRIFILL(20) TRIFILL(21) TRIFILL(22) TRIFILL(23) TRIFILL(24)
        TRIFILL(25) TRIFILL(26) TRIFILL(27) TRIFILL(28) TRIFILL(29)
        TRIFILL(30) TRIFILL(31) TRIFILL(32) TRIFILL(33) TRIFILL(34)
        TRIFILL(35) TRIFILL(36) TRIFILL(37) TRIFILL(38) TRIFILL(39)
        TRIFILL(40) TRIFILL(41) TRIFILL(42) TRIFILL(43) TRIFILL(44)
        #undef TRIFILL

        // Unnormalized ascending Horner, KTAY=5: A_j = A_{j-1}*G; R += (1/j!)*A_j.
        // pk phase first, then s phase: A01 and A2 never co-live -> lower
        // peak VGPR pressure (the streams are independent, math unchanged).
        {
            v2f A01[MM];
            trow_pk(Tri, A01, R01, R01, 1.0f);
            trow_pk(Tri, A01, R01, A01, 0.5f);
            trow_pk(Tri, A01, R01, A01, 0.16666667f);
            trow_pk(Tri, A01, R01, A01, 0.041666668f);
            trow_pk(Tri, A01, R01, A01, 0.0083333338f);
        }
        {
            float A2[MM];
            trow_s(Tri, A2, R2, R2, 1.0f);
            trow_s(Tri, A2, R2, A2, 0.5f);
            trow_s(Tri, A2, R2, A2, 0.16666667f);
            trow_s(Tri, A2, R2, A2, 0.041666668f);
            trow_s(Tri, A2, R2, A2, 0.0083333338f);
        }
    }

    // Store segment product: packed pair rows from all lanes, scalar from q<2
    {
        float* dst = &buf_s[seg * MATS];
        float4* d0 = reinterpret_cast<float4*>(dst + p0 * ROWP);
        d0[0] = make_float4(R01[0].x, R01[1].x, R01[2].x, R01[3].x);
        d0[1] = make_float4(R01[4].x, R01[5].x, R01[6].x, R01[7].x);
        d0[2] = make_float4(R01[8].x, R01[9].x, 0.0f, 0.0f);
        float4* d1 = reinterpret_cast<float4*>(dst + (p0 + 1) * ROWP);
        d1[0] = make_float4(R01[0].y, R01[1].y, R01[2].y, R01[3].y);
        d1[1] = make_float4(R01[4].y, R01[5].y, R01[6].y, R01[7].y);
        d1[2] = make_float4(R01[8].y, R01[9].y, 0.0f, 0.0f);
        if (hasS) {
            float4* d2 = reinterpret_cast<float4*>(dst + sr * ROWP);
            d2[0] = make_float4(R2[0], R2[1], R2[2], R2[3]);
            d2[1] = make_float4(R2[4], R2[5], R2[6], R2[7]);
            d2[2] = make_float4(R2[8], R2[9], 0.0f, 0.0f);
        }
    }
    __syncthreads();

    // Pair-style dyadic tree, 7 levels (128 -> 1 product at slot 0)
    #pragma unroll 1
    for (int span = 2; span <= SEGS; span <<= 1) {
        const int np = SEGS / span;
        if (tid < 2 * np) {
            const int pr = tid >> 1;
            const int pq = tid & 1;
            pair_combine(buf_s, pr * span, pr * span + (span >> 1), pq);
        }
        __syncthreads();
    }

    // Chunk product -> ws, padded 120 floats at (chain*NCHK + qt)
    if (tid < 30) {
        const float4 v = reinterpret_cast<const float4*>(buf_s)[tid];
        reinterpret_cast<float4*>(ws)[((size_t)chain * NCHK + qt) * 30 + tid] = v;
    }
}

// K2: one block per chain; combine its 4 chunk products (time order)
__global__ __launch_bounds__(256)
void dev_tree4(const float* __restrict__ ws, float* __restrict__ out)
{
    __shared__ __align__(16) float buf_s[4 * MATS];
    const int tid   = threadIdx.x;
    const int chain = blockIdx.x;

    if (tid < 120) {
        const int m  = tid / 30;
        const int o4 = tid - m * 30;
        const float4 v = reinterpret_cast<const float4*>(ws)[((size_t)chain * 4 + m) * 30 + o4];
        reinterpret_cast<float4*>(&buf_s[m * MATS])[o4] = v;
    }
    __syncthreads();

    if (tid < 4)
        pair_combine(buf_s, (tid >> 1) * 2, (tid >> 1) * 2 + 1, tid & 1);
    __syncthreads();
    if (tid < 2)
        pair_combine(buf_s, 0, 2, tid);
    __syncthreads();

    if (tid < 100) {
        const int i = tid / 10;
        const int j = tid - i * 10;
        out[(size_t)chain * 100 + tid] = buf_s[i * ROWP + j];
    }
}

extern "C" void kernel_launch(void* const* d_in, const int* in_sizes, int n_in,
                              void* d_out, int out_size, void* d_ws, size_t ws_size,
                              hipStream_t stream) {
    (void)in_sizes; (void)n_in; (void)out_size; (void)ws_size;
    const float* x = (const float*)d_in[0];  // (64, 2048, 8)
    const float* A = (const float*)d_in[1];  // (2, 8, 10, 10)
    float* out = (float*)d_out;              // (64, 2, 10, 10)
    float* ws  = (float*)d_ws;               // 512 mats * 480 B = 245,760 B

    dev_serial<<<dim3(NCHAIN * NCHK), dim3(BLK), 0, stream>>>(x, A, ws);
    dev_tree4<<<dim3(NCHAIN), dim3(256), 0, stream>>>(ws, out);
}

// Round 3
// 131.774 us; speedup vs baseline: 4.3598x; 4.3598x over previous
//
#include <hip/hip_runtime.h>

// Problem constants
#define NB     64      // batch
#define TT     2048    // time
#define INQ    8       // input size
#define CC     2       // channels
#define MM     10      // hidden m
#define ROWP   12      // padded row floats (48 B)
#define MATS   124     // matrix stride in LDS tree (124%32=28)
#define PSTR   20      // skp row stride floats (16B-aligned)
#define BLK    512     // threads per block (8 waves)
#define SEGS   128     // segments per block (512 thr / 4 lanes)
#define SLEN   4       // sequential steps per quad segment
#define NCHK   4       // chunks per chain -> grid 512, 2 blocks/CU, one round
#define NCHAIN (NB*CC)

typedef float v2f __attribute__((ext_vector_type(2)));

// Upper-triangle index for (k,j), k<j, into 45-element array
__device__ __forceinline__ constexpr int triIdx(int k, int j) {
    return k * 10 + j - ((k + 1) * (k + 2)) / 2;
}

// Broadcast lane (quad base + SRC)'s value to all 4 lanes of the quad.
template <int SRC>
__device__ __forceinline__ float dpp_qbcast(float v) {
    const int i = __float_as_int(v);
    const int r = __builtin_amdgcn_update_dpp(i, i, SRC * 0x55, 0xF, 0xF, true);
    return __int_as_float(r);
}

// One Taylor row-stream, packed pair of rows: t = S*G; A = t; R += cj*t.
// Row r of S*G depends only on row r of S -> in-place safe (S may alias A).
__device__ __forceinline__ void trow_pk(const float* __restrict__ Tri,
                                        v2f* A, v2f* R, const v2f* S, float cj) {
    v2f t[MM];
    t[0] = -S[1] * Tri[triIdx(0, 1)];
    #pragma unroll
    for (int j = 1; j < MM; ++j) t[j] = S[0] * Tri[triIdx(0, j)];
    #pragma unroll
    for (int k = 1; k < MM; ++k) {
        const v2f a = S[k];
        #pragma unroll
        for (int j = 0; j < MM; ++j) {
            if (k == j) continue;
            if (j == 0 && k == 1) continue;
            if (j > k) t[j] += a * Tri[triIdx(k, j)];
            else       t[j] -= a * Tri[triIdx(j, k)];
        }
    }
    #pragma unroll
    for (int j = 0; j < MM; ++j) { A[j] = t[j]; R[j] += cj * t[j]; }
}

__device__ __forceinline__ void trow_s(const float* __restrict__ Tri,
                                       float* A, float* R, const float* S, float cj) {
    float t[MM];
    t[0] = -S[1] * Tri[triIdx(0, 1)];
    #pragma unroll
    for (int j = 1; j < MM; ++j) t[j] = S[0] * Tri[triIdx(0, j)];
    #pragma unroll
    for (int k = 1; k < MM; ++k) {
        const float a = S[k];
        #pragma unroll
        for (int j = 0; j < MM; ++j) {
            if (k == j) continue;
            if (j == 0 && k == 1) continue;
            if (j > k) t[j] += a * Tri[triIdx(k, j)];
            else       t[j] -= a * Tri[triIdx(j, k)];
        }
    }
    #pragma unroll
    for (int j = 0; j < MM; ++j) { A[j] = t[j]; R[j] += cj * t[j]; }
}

// 2-lane pair combine: buf[ls] <- buf[ls] * buf[rs] (pq = which 5-row half)
__device__ __forceinline__ void pair_combine(float* buf_s, int ls, int rs, int pq) {
    float lrow[5][MM];
    #pragma unroll
    for (int r = 0; r < 5; ++r) {
        const float4* lr = reinterpret_cast<const float4*>(
            &buf_s[ls * MATS + (pq * 5 + r) * ROWP]);
        const float4 a = lr[0], b = lr[1], c4 = lr[2];
        lrow[r][0] = a.x;  lrow[r][1] = a.y;  lrow[r][2] = a.z;  lrow[r][3] = a.w;
        lrow[r][4] = b.x;  lrow[r][5] = b.y;  lrow[r][6] = b.z;  lrow[r][7] = b.w;
        lrow[r][8] = c4.x; lrow[r][9] = c4.y;
    }
    float d[5][MM];
    #pragma unroll
    for (int r = 0; r < 5; ++r)
        #pragma unroll
        for (int j = 0; j < MM; ++j)
            d[r][j] = 0.0f;
    #pragma unroll
    for (int k = 0; k < MM; ++k) {
        const float4* rr = reinterpret_cast<const float4*>(&buf_s[rs * MATS + k * ROWP]);
        const float4 a = rr[0], b = rr[1], c4 = rr[2];
        float rrow[MM];
        rrow[0] = a.x;  rrow[1] = a.y;  rrow[2] = a.z;  rrow[3] = a.w;
        rrow[4] = b.x;  rrow[5] = b.y;  rrow[6] = b.z;  rrow[7] = b.w;
        rrow[8] = c4.x; rrow[9] = c4.y;
        #pragma unroll
        for (int r = 0; r < 5; ++r) {
            const float lv = lrow[r][k];
            #pragma unroll
            for (int j = 0; j < MM; ++j)
                d[r][j] += lv * rrow[j];
        }
    }
    float* dst = &buf_s[ls * MATS + pq * 5 * ROWP];
    #pragma unroll
    for (int r = 0; r < 5; ++r) {
        float4* drow = reinterpret_cast<float4*>(dst + r * ROWP);
        drow[0] = make_float4(d[r][0], d[r][1], d[r][2], d[r][3]);
        drow[1] = make_float4(d[r][4], d[r][5], d[r][6], d[r][7]);
        drow[2] = make_float4(d[r][8], d[r][9], 0.0f, 0.0f);
    }
}

// r16: identical body to r15, launch bound fixed. r15 PROVED the second
// __launch_bounds__ arg is min BLOCKS/CU on this toolchain (CUDA semantics):
// (512,4) -> 4 blk x 8 waves = 32 waves/CU -> 64-VGPR cap -> 1.7 GB of spill
// traffic (FETCH 691 MB / WRITE 970 MB). (512,2) -> 2 blk x 8 waves =
// 16 waves/CU = 4 waves/SIMD -> 128-VGPR cap. Live-set: Tri(45)+R01(20)+
// R2(10) cross-phase + A01(20)+t(20) pk-peak ~= 125 -> fits 128.
// Structure: BLK=512/SEGS=128/SLEN=4/NCHK=4 keeps grid 512 = exactly
// 2 blocks/CU in ONE round with the same total tree work as r12.
// LDS 65,408 B x 2 blocks = 131 KB <= 160 KB.
// Taylor rows: q0 pk{0,1}+s{2}, q1 pk{3,4}+s{5}, q2 pk{6,7}, q3 pk{8,9}
// (q2/q3 scalar stream is dummy row 9). KTAY=5: trunc ~1.5e-6/step,
// ~3e-3 accumulated — inside the 1.95e-2 budget (absmax was 0.0078).
__global__ __launch_bounds__(BLK, 2)
void dev_serial(const float* __restrict__ x,
                const float* __restrict__ A,
                float* __restrict__ ws)
{
    __shared__ __align__(16) float skp_s[24 * PSTR];    // 1920 B pair-interleaved
    __shared__ __align__(16) float buf_s[SEGS * MATS];  // 63488 B tree buffer

    const int tid   = threadIdx.x;
    const int chain = blockIdx.x >> 2;   // / NCHK
    const int qt    = blockIdx.x & 3;
    const int n     = chain >> 1;        // / CC
    const int c     = chain & 1;

    // skp[p][ip] = v2f{ sktri[2p][ip], sktri[2p+1][ip] }, rows >=45 zero.
    for (int e = tid; e < 24 * 16; e += BLK) {
        const int p   = e >> 4;
        const int rem = e & 15;
        const int ip  = rem >> 1;
        const int h   = rem & 1;
        const int t   = 2 * p + h;
        float v = 0.0f;
        if (t < 45) {
            int k = 0, r2 = t;
            while (r2 >= 9 - k) { r2 -= (9 - k); ++k; }
            const int j = k + 1 + r2;
            const float* Ab = A + (size_t)(c * INQ + ip) * (MM * MM);
            v = Ab[k * MM + j] - Ab[j * MM + k];
        }
        skp_s[p * PSTR + 2 * ip + h] = v;
    }
    for (int p = tid; p < 24; p += BLK) {
        skp_s[p * PSTR + 16] = 0.0f; skp_s[p * PSTR + 17] = 0.0f;
        skp_s[p * PSTR + 18] = 0.0f; skp_s[p * PSTR + 19] = 0.0f;
    }
    __syncthreads();

    const int seg = tid >> 2;
    const int q   = tid & 3;                        // lane within quad
    const int p0  = (q < 2) ? 3 * q : (q == 2 ? 6 : 8);  // packed pair rows
    const int sr  = (q < 2) ? (3 * q + 2) : 9;      // scalar row (dummy on q>=2)
    const bool hasS = (q < 2);

    v2f   R01[MM];
    float R2[MM];
    #pragma unroll
    for (int j = 0; j < MM; ++j) {
        R01[j] = (v2f){ (j == p0) ? 1.0f : 0.0f, (j == p0 + 1) ? 1.0f : 0.0f };
        R2[j]  = (j == sr) ? 1.0f : 0.0f;
    }

    const float4* px = reinterpret_cast<const float4*>(x + (size_t)n * TT * INQ);
    const int t0 = qt * (SEGS * SLEN) + seg * SLEN;   // max t0 = 2044

    #pragma unroll 1
    for (int s = 0; s < SLEN; ++s) {
        // Fresh loads each step (no live x-state across the Taylor body):
        // t <= 2047; t+1 clamped to 2047 makes the last increment zero (=I).
        const int t = t0 + s;
        int t1 = t + 1; if (t1 > TT - 1) t1 = TT - 1;
        const float4 a0 = px[2 * t],  a1 = px[2 * t + 1];
        const float4 b0 = px[2 * t1], b1 = px[2 * t1 + 1];
        float dx[INQ];
        dx[0] = b0.x - a0.x; dx[1] = b0.y - a0.y;
        dx[2] = b0.z - a0.z; dx[3] = b0.w - a0.w;
        dx[4] = b1.x - a1.x; dx[5] = b1.y - a1.y;
        dx[6] = b1.z - a1.z; dx[7] = b1.w - a1.w;

        // Packed tv: tvp[pp] = (tri[12q+2pp], tri[12q+2pp+1])
        v2f tvp[6];
        #pragma unroll
        for (int pp = 0; pp < 6; ++pp) {
            const v2f* sp = reinterpret_cast<const v2f*>(&skp_s[(6 * q + pp) * PSTR]);
            v2f acc = dx[0] * sp[0];
            #pragma unroll
            for (int ip = 1; ip < INQ; ++ip)
                acc += dx[ip] * sp[ip];
            tvp[pp] = acc;
        }
        float tv[12];
        #pragma unroll
        for (int pp = 0; pp < 6; ++pp) { tv[2 * pp] = tvp[pp].x; tv[2 * pp + 1] = tvp[pp].y; }

        // Assemble Tri[45] per-lane via DPP quad broadcast
        float Tri[45];
        #define TRIFILL(U) Tri[U] = dpp_qbcast<(U) / 12>(tv[(U) % 12]);
        TRIFILL(0)  TRIFILL(1)  TRIFILL(2)  TRIFILL(3)  TRIFILL(4)
        TRIFILL(5)  TRIFILL(6)  TRIFILL(7)  TRIFILL(8)  TRIFILL(9)
        TRIFILL(10) TRIFILL(11) TRIFILL(12) TRIFILL(13) TRIFILL(14)
        TRIFILL(15) TRIFILL(16) TRIFILL(17) TRIFILL(18) TRIFILL(19)
        TRIFILL(20) TRIFILL(21) TRIFILL(22) TRIFILL(23) TRIFILL(24)
        TRIFILL(25) TRIFILL(26) TRIFILL(27) TRIFILL(28) TRIFILL(29)
        TRIFILL(30) TRIFILL(31) TRIFILL(32) TRIFILL(33) TRIFILL(34)
        TRIFILL(35) TRIFILL(36) TRIFILL(37) TRIFILL(38) TRIFILL(39)
        TRIFILL(40) TRIFILL(41) TRIFILL(42) TRIFILL(43) TRIFILL(44)
        #undef TRIFILL

        // Unnormalized ascending Horner, KTAY=5: A_j = A_{j-1}*G; R += (1/j!)*A_j.
        // pk phase first, then s phase: A01 and A2 never co-live -> lower
        // peak VGPR pressure (the streams are independent, math unchanged).
        {
            v2f A01[MM];
            trow_pk(Tri, A01, R01, R01, 1.0f);
            trow_pk(Tri, A01, R01, A01, 0.5f);
            trow_pk(Tri, A01, R01, A01, 0.16666667f);
            trow_pk(Tri, A01, R01, A01, 0.041666668f);
            trow_pk(Tri, A01, R01, A01, 0.0083333338f);
        }
        {
            float A2[MM];
            trow_s(Tri, A2, R2, R2, 1.0f);
            trow_s(Tri, A2, R2, A2, 0.5f);
            trow_s(Tri, A2, R2, A2, 0.16666667f);
            trow_s(Tri, A2, R2, A2, 0.041666668f);
            trow_s(Tri, A2, R2, A2, 0.0083333338f);
        }
    }

    // Store segment product: packed pair rows from all lanes, scalar from q<2
    {
        float* dst = &buf_s[seg * MATS];
        float4* d0 = reinterpret_cast<float4*>(dst + p0 * ROWP);
        d0[0] = make_float4(R01[0].x, R01[1].x, R01[2].x, R01[3].x);
        d0[1] = make_float4(R01[4].x, R01[5].x, R01[6].x, R01[7].x);
        d0[2] = make_float4(R01[8].x, R01[9].x, 0.0f, 0.0f);
        float4* d1 = reinterpret_cast<float4*>(dst + (p0 + 1) * ROWP);
        d1[0] = make_float4(R01[0].y, R01[1].y, R01[2].y, R01[3].y);
        d1[1] = make_float4(R01[4].y, R01[5].y, R01[6].y, R01[7].y);
        d1[2] = make_float4(R01[8].y, R01[9].y, 0.0f, 0.0f);
        if (hasS) {
            float4* d2 = reinterpret_cast<float4*>(dst + sr * ROWP);
            d2[0] = make_float4(R2[0], R2[1], R2[2], R2[3]);
            d2[1] = make_float4(R2[4], R2[5], R2[6], R2[7]);
            d2[2] = make_float4(R2[8], R2[9], 0.0f, 0.0f);
        }
    }
    __syncthreads();

    // Pair-style dyadic tree, 7 levels (128 -> 1 product at slot 0)
    #pragma unroll 1
    for (int span = 2; span <= SEGS; span <<= 1) {
        const int np = SEGS / span;
        if (tid < 2 * np) {
            const int pr = tid >> 1;
            const int pq = tid & 1;
            pair_combine(buf_s, pr * span, pr * span + (span >> 1), pq);
        }
        __syncthreads();
    }

    // Chunk product -> ws, padded 120 floats at (chain*NCHK + qt)
    if (tid < 30) {
        const float4 v = reinterpret_cast<const float4*>(buf_s)[tid];
        reinterpret_cast<float4*>(ws)[((size_t)chain * NCHK + qt) * 30 + tid] = v;
    }
}

// K2: one block per chain; combine its 4 chunk products (time order)
__global__ __launch_bounds__(256)
void dev_tree4(const float* __restrict__ ws, float* __restrict__ out)
{
    __shared__ __align__(16) float buf_s[4 * MATS];
    const int tid   = threadIdx.x;
    const int chain = blockIdx.x;

    if (tid < 120) {
        const int m  = tid / 30;
        const int o4 = tid - m * 30;
        const float4 v = reinterpret_cast<const float4*>(ws)[((size_t)chain * 4 + m) * 30 + o4];
        reinterpret_cast<float4*>(&buf_s[m * MATS])[o4] = v;
    }
    __syncthreads();

    if (tid < 4)
        pair_combine(buf_s, (tid >> 1) * 2, (tid >> 1) * 2 + 1, tid & 1);
    __syncthreads();
    if (tid < 2)
        pair_combine(buf_s, 0, 2, tid);
    __syncthreads();

    if (tid < 100) {
        const int i = tid / 10;
        const int j = tid - i * 10;
        out[(size_t)chain * 100 + tid] = buf_s[i * ROWP + j];
    }
}

extern "C" void kernel_launch(void* const* d_in, const int* in_sizes, int n_in,
                              void* d_out, int out_size, void* d_ws, size_t ws_size,
                              hipStream_t stream) {
    (void)in_sizes; (void)n_in; (void)out_size; (void)ws_size;
    const float* x = (const float*)d_in[0];  // (64, 2048, 8)
    const float* A = (const float*)d_in[1];  // (2, 8, 10, 10)
    float* out = (float*)d_out;              // (64, 2, 10, 10)
    float* ws  = (float*)d_ws;               // 512 mats * 480 B = 245,760 B

    dev_serial<<<dim3(NCHAIN * NCHK), dim3(BLK), 0, stream>>>(x, A, ws);
    dev_tree4<<<dim3(NCHAIN), dim3(256), 0, stream>>>(ws, out);
}

// Round 4
// 109.791 us; speedup vs baseline: 5.2327x; 1.2002x over previous
//
#include <hip/hip_runtime.h>

// Problem constants
#define NB     64      // batch
#define TT     2048    // time
#define INQ    8       // input size
#define CC     2       // channels
#define MM     10      // hidden m
#define ROWP   12      // padded row floats (48 B)
#define MATS   124     // matrix stride in LDS tree (124%32=28)
#define SKST   12      // skq row stride floats (48 B, b128-aligned)
#define BLK    512     // threads per block (8 waves)
#define SEGS   96      // 8 waves * 12 five-lane groups
#define SLEN   6       // steps per segment (padded timeline 2304 = 4*96*6)
#define NCHK   4       // chunks per chain -> grid 512, 2 blocks/CU, one round
#define NCHAIN (NB*CC)

typedef float v2f __attribute__((ext_vector_type(2)));

// Upper-triangle index for (k,j), k<j, into 45-element array
__device__ __forceinline__ constexpr int triIdx(int k, int j) {
    return k * 10 + j - ((k + 1) * (k + 2)) / 2;
}

// In-wave gather: pull value of register v from wave-lane (addr_bytes>>2).
__device__ __forceinline__ float bperm_f(int addr_bytes, float v) {
    return __int_as_float(__builtin_amdgcn_ds_bpermute(addr_bytes, __float_as_int(v)));
}

// One Taylor row-stream, packed pair of rows: t = S*G; A = t; R += cj*t.
// Row r of S*G depends only on row r of S -> in-place safe (S may alias A).
__device__ __forceinline__ void trow_pk(const float* __restrict__ Tri,
                                        v2f* A, v2f* R, const v2f* S, float cj) {
    v2f t[MM];
    t[0] = -S[1] * Tri[triIdx(0, 1)];
    #pragma unroll
    for (int j = 1; j < MM; ++j) t[j] = S[0] * Tri[triIdx(0, j)];
    #pragma unroll
    for (int k = 1; k < MM; ++k) {
        const v2f a = S[k];
        #pragma unroll
        for (int j = 0; j < MM; ++j) {
            if (k == j) continue;
            if (j == 0 && k == 1) continue;
            if (j > k) t[j] += a * Tri[triIdx(k, j)];
            else       t[j] -= a * Tri[triIdx(j, k)];
        }
    }
    #pragma unroll
    for (int j = 0; j < MM; ++j) { A[j] = t[j]; R[j] += cj * t[j]; }
}

// 2-lane pair combine: buf[ls] <- buf[ls] * buf[rs] (pq = which 5-row half)
__device__ __forceinline__ void pair_combine(float* buf_s, int ls, int rs, int pq) {
    float lrow[5][MM];
    #pragma unroll
    for (int r = 0; r < 5; ++r) {
        const float4* lr = reinterpret_cast<const float4*>(
            &buf_s[ls * MATS + (pq * 5 + r) * ROWP]);
        const float4 a = lr[0], b = lr[1], c4 = lr[2];
        lrow[r][0] = a.x;  lrow[r][1] = a.y;  lrow[r][2] = a.z;  lrow[r][3] = a.w;
        lrow[r][4] = b.x;  lrow[r][5] = b.y;  lrow[r][6] = b.z;  lrow[r][7] = b.w;
        lrow[r][8] = c4.x; lrow[r][9] = c4.y;
    }
    float d[5][MM];
    #pragma unroll
    for (int r = 0; r < 5; ++r)
        #pragma unroll
        for (int j = 0; j < MM; ++j)
            d[r][j] = 0.0f;
    #pragma unroll
    for (int k = 0; k < MM; ++k) {
        const float4* rr = reinterpret_cast<const float4*>(&buf_s[rs * MATS + k * ROWP]);
        const float4 a = rr[0], b = rr[1], c4 = rr[2];
        float rrow[MM];
        rrow[0] = a.x;  rrow[1] = a.y;  rrow[2] = a.z;  rrow[3] = a.w;
        rrow[4] = b.x;  rrow[5] = b.y;  rrow[6] = b.z;  rrow[7] = b.w;
        rrow[8] = c4.x; rrow[9] = c4.y;
        #pragma unroll
        for (int r = 0; r < 5; ++r) {
            const float lv = lrow[r][k];
            #pragma unroll
            for (int j = 0; j < MM; ++j)
                d[r][j] += lv * rrow[j];
        }
    }
    float* dst = &buf_s[ls * MATS + pq * 5 * ROWP];
    #pragma unroll
    for (int r = 0; r < 5; ++r) {
        float4* drow = reinterpret_cast<float4*>(dst + r * ROWP);
        drow[0] = make_float4(d[r][0], d[r][1], d[r][2], d[r][3]);
        drow[1] = make_float4(d[r][4], d[r][5], d[r][6], d[r][7]);
        drow[2] = make_float4(d[r][8], d[r][9], 0.0f, 0.0f);
    }
}

// r17: 5-lane all-packed decomposition. The quad split wasted 25% of Taylor
// slots on a dummy scalar stream (q2/q3) and carried R01+R2+A01+A2 = 80 regs
// + Tri 45 -> true live ~140 (r16 spilled 33MB fetch / 58MB write under the
// 128 cap). New split: 5 lanes per matrix, each owning ONE v2f row-pair ->
// all-pk streams, zero dummy work, live set R(20)+A(20)+t(20)+Tri(45) ~ 118.
// Tri broadcast: quad-DPP can't span 5 lanes -> 45x in-wave ds_bpermute
// (producer lane g*5+e/9, reg e%9); tv inputs from e-major skq[45][SKST] LDS
// (2x ds_read_b128/entry; same-group lanes broadcast, rows spread banks).
// Geometry: 8 waves x 12 groups = 96 segs (4 idle lanes/wave = 6% waste);
// timeline padded 2304 = NCHK*96*6 -> uniform SLEN=6 (clamped loads give
// dx=0 -> exp=I on pad steps, exact). Grid 512 = 2 blocks/CU; LDS 49.8 KB.
// __launch_bounds__(512,2): 2 blk x 8 waves = 16 waves/CU -> 128-VGPR cap
// (semantics HW-confirmed in r16). KTAY=5 unchanged.
__global__ __launch_bounds__(BLK, 2)
void dev_serial(const float* __restrict__ x,
                const float* __restrict__ A,
                float* __restrict__ ws)
{
    __shared__ __align__(16) float skq_s[45 * SKST];    // 2160 B, e-major
    __shared__ __align__(16) float buf_s[SEGS * MATS];  // 47616 B tree buffer

    const int tid   = threadIdx.x;
    const int chain = blockIdx.x >> 2;   // / NCHK
    const int qt    = blockIdx.x & 3;
    const int n     = chain >> 1;        // / CC
    const int c     = chain & 1;

    // skq[e][ip] = sk-tri entry e of input dim ip (channel c). 360 entries.
    if (tid < 45 * 8) {
        const int e  = tid >> 3;
        const int ip = tid & 7;
        int k = 0, r2 = e;
        while (r2 >= 9 - k) { r2 -= (9 - k); ++k; }
        const int j = k + 1 + r2;
        const float* Ab = A + (size_t)(c * INQ + ip) * (MM * MM);
        skq_s[e * SKST + ip] = Ab[k * MM + j] - Ab[j * MM + k];
    }
    __syncthreads();

    const int wv  = tid >> 6;            // wave 0..7
    const int wl  = tid & 63;            // lane in wave
    const int g   = wl / 5;              // group 0..11 (12 = inactive tail)
    const int r   = wl - 5 * g;          // role 0..4 -> owns rows {2r, 2r+1}
    const bool act = (wl < 60);
    const int seg = wv * 12 + g;         // 0..95 active (96+ = harmless)
    const int p0  = 2 * r;

    v2f R01[MM];
    #pragma unroll
    for (int j = 0; j < MM; ++j)
        R01[j] = (v2f){ (j == p0) ? 1.0f : 0.0f, (j == p0 + 1) ? 1.0f : 0.0f };

    const float4* px = reinterpret_cast<const float4*>(x + (size_t)n * TT * INQ);
    const int t0 = qt * (SEGS * SLEN) + seg * SLEN;   // padded timeline, <=2304

    #pragma unroll 1
    for (int s = 0; s < SLEN; ++s) {
        // Clamped fresh loads; pad steps (t >= 2047) give dx = 0 -> exp = I.
        const int t = t0 + s;
        const int tc = (t     > TT - 1) ? TT - 1 : t;
        const int t1 = (t + 1 > TT - 1) ? TT - 1 : t + 1;
        const float4 a0 = px[2 * tc], a1 = px[2 * tc + 1];
        const float4 b0 = px[2 * t1], b1 = px[2 * t1 + 1];
        float dx[INQ];
        dx[0] = b0.x - a0.x; dx[1] = b0.y - a0.y;
        dx[2] = b0.z - a0.z; dx[3] = b0.w - a0.w;
        dx[4] = b1.x - a1.x; dx[5] = b1.y - a1.y;
        dx[6] = b1.z - a1.z; dx[7] = b1.w - a1.w;

        // This lane's 9 tri entries: e = 9r+i, tvv[i] = dx . skq[e][:]
        float tvv[9];
        {
            const float* srow = &skq_s[(9 * r) * SKST];
            #pragma unroll
            for (int i = 0; i < 9; ++i) {
                const float4 s0 = *reinterpret_cast<const float4*>(srow + i * SKST);
                const float4 s1 = *reinterpret_cast<const float4*>(srow + i * SKST + 4);
                tvv[i] = dx[0] * s0.x + dx[1] * s0.y + dx[2] * s0.z + dx[3] * s0.w
                       + dx[4] * s1.x + dx[5] * s1.y + dx[6] * s1.z + dx[7] * s1.w;
            }
        }

        // Assemble Tri[45]: entry e lives on wave-lane g*5 + e/9, reg e%9.
        float Tri[45];
        const int base = (wl - r) * 4;   // = g*5*4, group-base byte address
        #pragma unroll
        for (int e = 0; e < 45; ++e)
            Tri[e] = bperm_f(base + (e / 9) * 4, tvv[e % 9]);

        // Unnormalized ascending Horner, KTAY=5: A_j = A_{j-1}*G; R += (1/j!)A_j
        v2f A01[MM];
        trow_pk(Tri, A01, R01, R01, 1.0f);
        trow_pk(Tri, A01, R01, A01, 0.5f);
        trow_pk(Tri, A01, R01, A01, 0.16666667f);
        trow_pk(Tri, A01, R01, A01, 0.041666668f);
        trow_pk(Tri, A01, R01, A01, 0.0083333338f);
    }

    // Store segment product: each active lane stores its pair of rows.
    if (act) {
        float* dst = &buf_s[seg * MATS];
        float4* d0 = reinterpret_cast<float4*>(dst + p0 * ROWP);
        d0[0] = make_float4(R01[0].x, R01[1].x, R01[2].x, R01[3].x);
        d0[1] = make_float4(R01[4].x, R01[5].x, R01[6].x, R01[7].x);
        d0[2] = make_float4(R01[8].x, R01[9].x, 0.0f, 0.0f);
        float4* d1 = reinterpret_cast<float4*>(dst + (p0 + 1) * ROWP);
        d1[0] = make_float4(R01[0].y, R01[1].y, R01[2].y, R01[3].y);
        d1[1] = make_float4(R01[4].y, R01[5].y, R01[6].y, R01[7].y);
        d1[2] = make_float4(R01[8].y, R01[9].y, 0.0f, 0.0f);
    }
    __syncthreads();

    // Dyadic tree on 96 leaves: spans 2..32 -> products at {0,32,64},
    // then (0*32) and (0*64) sequential tail (time order preserved).
    #pragma unroll 1
    for (int span = 2; span <= 32; span <<= 1) {
        const int np = SEGS / span;
        if (tid < 2 * np) {
            const int pr = tid >> 1;
            const int pq = tid & 1;
            pair_combine(buf_s, pr * span, pr * span + (span >> 1), pq);
        }
        __syncthreads();
    }
    if (tid < 2) pair_combine(buf_s, 0, 32, tid);
    __syncthreads();
    if (tid < 2) pair_combine(buf_s, 0, 64, tid);
    __syncthreads();

    // Chunk product -> ws, padded 120 floats at (chain*NCHK + qt)
    if (tid < 30) {
        const float4 v = reinterpret_cast<const float4*>(buf_s)[tid];
        reinterpret_cast<float4*>(ws)[((size_t)chain * NCHK + qt) * 30 + tid] = v;
    }
}

// K2: one block per chain; combine its 4 chunk products (time order)
__global__ __launch_bounds__(256)
void dev_tree4(const float* __restrict__ ws, float* __restrict__ out)
{
    __shared__ __align__(16) float buf_s[4 * MATS];
    const int tid   = threadIdx.x;
    const int chain = blockIdx.x;

    if (tid < 120) {
        const int m  = tid / 30;
        const int o4 = tid - m * 30;
        const float4 v = reinterpret_cast<const float4*>(ws)[((size_t)chain * 4 + m) * 30 + o4];
        reinterpret_cast<float4*>(&buf_s[m * MATS])[o4] = v;
    }
    __syncthreads();

    if (tid < 4)
        pair_combine(buf_s, (tid >> 1) * 2, (tid >> 1) * 2 + 1, tid & 1);
    __syncthreads();
    if (tid < 2)
        pair_combine(buf_s, 0, 2, tid);
    __syncthreads();

    if (tid < 100) {
        const int i = tid / 10;
        const int j = tid - i * 10;
        out[(size_t)chain * 100 + tid] = buf_s[i * ROWP + j];
    }
}

extern "C" void kernel_launch(void* const* d_in, const int* in_sizes, int n_in,
                              void* d_out, int out_size, void* d_ws, size_t ws_size,
                              hipStream_t stream) {
    (void)in_sizes; (void)n_in; (void)out_size; (void)ws_size;
    const float* x = (const float*)d_in[0];  // (64, 2048, 8)
    const float* A = (const float*)d_in[1];  // (2, 8, 10, 10)
    float* out = (float*)d_out;              // (64, 2, 10, 10)
    float* ws  = (float*)d_ws;               // 512 mats * 480 B = 245,760 B

    dev_serial<<<dim3(NCHAIN * NCHK), dim3(BLK), 0, stream>>>(x, A, ws);
    dev_tree4<<<dim3(NCHAIN), dim3(256), 0, stream>>>(ws, out);
}

// Round 6
// 97.311 us; speedup vs baseline: 5.9038x; 1.1282x over previous
//
#include <hip/hip_runtime.h>

// Problem constants
#define NB     64      // batch
#define TT     2048    // time
#define INQ    8       // input size
#define CC     2       // channels
#define MM     10      // hidden m
#define ROWP   12      // padded row floats (48 B)
#define MATS   124     // matrix stride in LDS tree (124%32=28)
#define SKST   12      // skq row stride floats (48 B, b128-aligned)
#define BLK    512     // threads per block (8 waves)
#define SEGS   96      // 8 waves * 12 five-lane groups
#define SLEN   11      // steps per segment (padded timeline 2112 = 2*96*11, 3% pad)
#define NCHK   2       // chunks per chain -> grid 256 = 1 block/CU
#define NCHAIN (NB*CC)

typedef float v2f __attribute__((ext_vector_type(2)));

// Upper-triangle index for (k,j), k<j, into 45-element array
__device__ __forceinline__ constexpr int triIdx(int k, int j) {
    return k * 10 + j - ((k + 1) * (k + 2)) / 2;
}

// In-wave gather: pull value of register v from wave-lane (addr_bytes>>2).
__device__ __forceinline__ float bperm_f(int addr_bytes, float v) {
    return __int_as_float(__builtin_amdgcn_ds_bpermute(addr_bytes, __float_as_int(v)));
}

// One Taylor row-stream, packed pair of rows: t = S*G; A = t; R += cj*t.
// Row r of S*G depends only on row r of S -> in-place safe (S may alias A).
__device__ __forceinline__ void trow_pk(const float* __restrict__ Tri,
                                        v2f* A, v2f* R, const v2f* S, float cj) {
    v2f t[MM];
    t[0] = -S[1] * Tri[triIdx(0, 1)];
    #pragma unroll
    for (int j = 1; j < MM; ++j) t[j] = S[0] * Tri[triIdx(0, j)];
    #pragma unroll
    for (int k = 1; k < MM; ++k) {
        const v2f a = S[k];
        #pragma unroll
        for (int j = 0; j < MM; ++j) {
            if (k == j) continue;
            if (j == 0 && k == 1) continue;
            if (j > k) t[j] += a * Tri[triIdx(k, j)];
            else       t[j] -= a * Tri[triIdx(j, k)];
        }
    }
    #pragma unroll
    for (int j = 0; j < MM; ++j) { A[j] = t[j]; R[j] += cj * t[j]; }
}

// 2-lane pair combine: buf[ls] <- buf[ls] * buf[rs] (pq = which 5-row half)
__device__ __forceinline__ void pair_combine(float* buf_s, int ls, int rs, int pq) {
    float lrow[5][MM];
    #pragma unroll
    for (int r = 0; r < 5; ++r) {
        const float4* lr = reinterpret_cast<const float4*>(
            &buf_s[ls * MATS + (pq * 5 + r) * ROWP]);
        const float4 a = lr[0], b = lr[1], c4 = lr[2];
        lrow[r][0] = a.x;  lrow[r][1] = a.y;  lrow[r][2] = a.z;  lrow[r][3] = a.w;
        lrow[r][4] = b.x;  lrow[r][5] = b.y;  lrow[r][6] = b.z;  lrow[r][7] = b.w;
        lrow[r][8] = c4.x; lrow[r][9] = c4.y;
    }
    float d[5][MM];
    #pragma unroll
    for (int r = 0; r < 5; ++r)
        #pragma unroll
        for (int j = 0; j < MM; ++j)
            d[r][j] = 0.0f;
    #pragma unroll
    for (int k = 0; k < MM; ++k) {
        const float4* rr = reinterpret_cast<const float4*>(&buf_s[rs * MATS + k * ROWP]);
        const float4 a = rr[0], b = rr[1], c4 = rr[2];
        float rrow[MM];
        rrow[0] = a.x;  rrow[1] = a.y;  rrow[2] = a.z;  rrow[3] = a.w;
        rrow[4] = b.x;  rrow[5] = b.y;  rrow[6] = b.z;  rrow[7] = b.w;
        rrow[8] = c4.x; rrow[9] = c4.y;
        #pragma unroll
        for (int r = 0; r < 5; ++r) {
            const float lv = lrow[r][k];
            #pragma unroll
            for (int j = 0; j < MM; ++j)
                d[r][j] += lv * rrow[j];
        }
    }
    float* dst = &buf_s[ls * MATS + pq * 5 * ROWP];
    #pragma unroll
    for (int r = 0; r < 5; ++r) {
        float4* drow = reinterpret_cast<float4*>(dst + r * ROWP);
        drow[0] = make_float4(d[r][0], d[r][1], d[r][2], d[r][3]);
        drow[1] = make_float4(d[r][4], d[r][5], d[r][6], d[r][7]);
        drow[2] = make_float4(d[r][8], d[r][9], 0.0f, 0.0f);
    }
}

// r18 (resubmit — prior run died to a container-level infra failure, no
// kernel verdict; code audited, no hang hazard found, so the experiment
// re-runs unchanged). Geometry round: r17 vs r12 proved occupancy is NOT
// the limiter (2x waves, same 60.6 us; VALU-busy-time conserved ~26-30 us
// in every config) -> levers are steps/CU, tree count, per-step cost.
// NCHK=2, SLEN=11 -> padded timeline 2112 (3.0% waste vs 12.5% at
// SLEN=6/NCHK=4), grid 256 = 1 block/CU, HALF the tree instances (256 vs
// 512), K2 reduced to a single combine. Uniform SLEN (not mixed 5/6)
// because intra-block barriers convert mixed lengths back into max-wave
// time. launch_bounds (512,1): with 1 block/CU the 128-VGPR cap is
// pointless; give the allocator room (spill = the r16 catastrophe;
// litmus = FETCH_SIZE stays ~4.3 MB). s_setprio(1) wraps the Taylor
// burst (T5). KTAY=5 unchanged (KTAY=4 is the prepared next move:
// ~-15% trow work, ~+7e-3 absmax risk vs 0.0195 budget).
__global__ __launch_bounds__(BLK, 1)
void dev_serial(const float* __restrict__ x,
                const float* __restrict__ A,
                float* __restrict__ ws)
{
    __shared__ __align__(16) float skq_s[45 * SKST];    // 2160 B, e-major
    __shared__ __align__(16) float buf_s[SEGS * MATS];  // 47616 B tree buffer

    const int tid   = threadIdx.x;
    const int chain = blockIdx.x >> 1;   // / NCHK
    const int qt    = blockIdx.x & 1;
    const int n     = chain >> 1;        // / CC
    const int c     = chain & 1;

    // skq[e][ip] = sk-tri entry e of input dim ip (channel c). 360 entries.
    if (tid < 45 * 8) {
        const int e  = tid >> 3;
        const int ip = tid & 7;
        int k = 0, r2 = e;
        while (r2 >= 9 - k) { r2 -= (9 - k); ++k; }
        const int j = k + 1 + r2;
        const float* Ab = A + (size_t)(c * INQ + ip) * (MM * MM);
        skq_s[e * SKST + ip] = Ab[k * MM + j] - Ab[j * MM + k];
    }
    __syncthreads();

    const int wv  = tid >> 6;            // wave 0..7
    const int wl  = tid & 63;            // lane in wave
    const int g   = wl / 5;              // group 0..11 (12 = inactive tail)
    const int r   = wl - 5 * g;          // role 0..4 -> owns rows {2r, 2r+1}
    const bool act = (wl < 60);
    const int seg = wv * 12 + g;         // 0..95 active (96+ = harmless)
    const int p0  = 2 * r;

    v2f R01[MM];
    #pragma unroll
    for (int j = 0; j < MM; ++j)
        R01[j] = (v2f){ (j == p0) ? 1.0f : 0.0f, (j == p0 + 1) ? 1.0f : 0.0f };

    const float4* px = reinterpret_cast<const float4*>(x + (size_t)n * TT * INQ);
    const int t0 = qt * (SEGS * SLEN) + seg * SLEN;   // padded timeline, < 2112

    #pragma unroll 1
    for (int s = 0; s < SLEN; ++s) {
        // Clamped fresh loads; pad steps (t >= 2047) give dx = 0 -> exp = I.
        const int t = t0 + s;
        const int tc = (t     > TT - 1) ? TT - 1 : t;
        const int t1 = (t + 1 > TT - 1) ? TT - 1 : t + 1;
        const float4 a0 = px[2 * tc], a1 = px[2 * tc + 1];
        const float4 b0 = px[2 * t1], b1 = px[2 * t1 + 1];
        float dx[INQ];
        dx[0] = b0.x - a0.x; dx[1] = b0.y - a0.y;
        dx[2] = b0.z - a0.z; dx[3] = b0.w - a0.w;
        dx[4] = b1.x - a1.x; dx[5] = b1.y - a1.y;
        dx[6] = b1.z - a1.z; dx[7] = b1.w - a1.w;

        // This lane's 9 tri entries: e = 9r+i, tvv[i] = dx . skq[e][:]
        float tvv[9];
        {
            const float* srow = &skq_s[(9 * r) * SKST];
            #pragma unroll
            for (int i = 0; i < 9; ++i) {
                const float4 s0 = *reinterpret_cast<const float4*>(srow + i * SKST);
                const float4 s1 = *reinterpret_cast<const float4*>(srow + i * SKST + 4);
                tvv[i] = dx[0] * s0.x + dx[1] * s0.y + dx[2] * s0.z + dx[3] * s0.w
                       + dx[4] * s1.x + dx[5] * s1.y + dx[6] * s1.z + dx[7] * s1.w;
            }
        }

        // Assemble Tri[45]: entry e lives on wave-lane g*5 + e/9, reg e%9.
        float Tri[45];
        const int base = (wl - r) * 4;   // = g*5*4, group-base byte address
        #pragma unroll
        for (int e = 0; e < 45; ++e)
            Tri[e] = bperm_f(base + (e / 9) * 4, tvv[e % 9]);

        // Unnormalized ascending Horner, KTAY=5: A_j = A_{j-1}*G; R += (1/j!)A_j
        __builtin_amdgcn_s_setprio(1);
        v2f A01[MM];
        trow_pk(Tri, A01, R01, R01, 1.0f);
        trow_pk(Tri, A01, R01, A01, 0.5f);
        trow_pk(Tri, A01, R01, A01, 0.16666667f);
        trow_pk(Tri, A01, R01, A01, 0.041666668f);
        trow_pk(Tri, A01, R01, A01, 0.0083333338f);
        __builtin_amdgcn_s_setprio(0);
    }

    // Store segment product: each active lane stores its pair of rows.
    if (act) {
        float* dst = &buf_s[seg * MATS];
        float4* d0 = reinterpret_cast<float4*>(dst + p0 * ROWP);
        d0[0] = make_float4(R01[0].x, R01[1].x, R01[2].x, R01[3].x);
        d0[1] = make_float4(R01[4].x, R01[5].x, R01[6].x, R01[7].x);
        d0[2] = make_float4(R01[8].x, R01[9].x, 0.0f, 0.0f);
        float4* d1 = reinterpret_cast<float4*>(dst + (p0 + 1) * ROWP);
        d1[0] = make_float4(R01[0].y, R01[1].y, R01[2].y, R01[3].y);
        d1[1] = make_float4(R01[4].y, R01[5].y, R01[6].y, R01[7].y);
        d1[2] = make_float4(R01[8].y, R01[9].y, 0.0f, 0.0f);
    }
    __syncthreads();

    // Dyadic tree on 96 leaves: spans 2..32 -> products at {0,32,64},
    // then (0*32) and (0*64) sequential tail (time order preserved).
    #pragma unroll 1
    for (int span = 2; span <= 32; span <<= 1) {
        const int np = SEGS / span;
        if (tid < 2 * np) {
            const int pr = tid >> 1;
            const int pq = tid & 1;
            pair_combine(buf_s, pr * span, pr * span + (span >> 1), pq);
        }
        __syncthreads();
    }
    if (tid < 2) pair_combine(buf_s, 0, 32, tid);
    __syncthreads();
    if (tid < 2) pair_combine(buf_s, 0, 64, tid);
    __syncthreads();

    // Chunk product -> ws, padded 120 floats at (chain*NCHK + qt)
    if (tid < 30) {
        const float4 v = reinterpret_cast<const float4*>(buf_s)[tid];
        reinterpret_cast<float4*>(ws)[((size_t)chain * NCHK + qt) * 30 + tid] = v;
    }
}

// K2: one block per chain; combine its 2 chunk products (time order)
__global__ __launch_bounds__(256)
void dev_tree2(const float* __restrict__ ws, float* __restrict__ out)
{
    __shared__ __align__(16) float buf_s[2 * MATS];
    const int tid   = threadIdx.x;
    const int chain = blockIdx.x;

    if (tid < 60) {
        const int m  = tid / 30;
        const int o4 = tid - m * 30;
        const float4 v = reinterpret_cast<const float4*>(ws)[((size_t)chain * 2 + m) * 30 + o4];
        reinterpret_cast<float4*>(&buf_s[m * MATS])[o4] = v;
    }
    __syncthreads();

    if (tid < 2)
        pair_combine(buf_s, 0, 1, tid);
    __syncthreads();

    if (tid < 100) {
        const int i = tid / 10;
        const int j = tid - i * 10;
        out[(size_t)chain * 100 + tid] = buf_s[i * ROWP + j];
    }
}

extern "C" void kernel_launch(void* const* d_in, const int* in_sizes, int n_in,
                              void* d_out, int out_size, void* d_ws, size_t ws_size,
                              hipStream_t stream) {
    (void)in_sizes; (void)n_in; (void)out_size; (void)ws_size;
    const float* x = (const float*)d_in[0];  // (64, 2048, 8)
    const float* A = (const float*)d_in[1];  // (2, 8, 10, 10)
    float* out = (float*)d_out;              // (64, 2, 10, 10)
    float* ws  = (float*)d_ws;               // 256 mats * 480 B = 122,880 B

    dev_serial<<<dim3(NCHAIN * NCHK), dim3(BLK), 0, stream>>>(x, A, ws);
    dev_tree2<<<dim3(NCHAIN), dim3(256), 0, stream>>>(ws, out);
}